// Round 4
// baseline (78.827 us; speedup 1.0000x reference)
//
#include <hip/hip_runtime.h>

// GE2E loss, N=1024 spk, M=32 utt, D=512.
// v4: A-resident GEMM with counted-vmcnt pipeline.
//  prep: emb fp32 -> ebf bf16 (32 MB) + ck bf16 (scaled sgn(lw)/32).
//  gemm: block = 128 rows x all 1024 cols. A (128x512 bf16 = 128 KB) staged
//        once via global_load_lds (pre-swizzled source, slot-XOR layout);
//        B ring-2 x 16 KB chunks (256 cols x 32 k, [kc][col] conflict-free
//        layout), prefetch 1 step ahead, s_waitcnt vmcnt(2) + raw s_barrier
//        (no __syncthreads full-drain in the loop). Wave tile 64x64,
//        16x16x32 bf16 MFMA. Row max / own / loss / acc finished in-block.

#define N_SPK 1024
#define M_UTT 32
#define D_DIM 512
#define NROWS (N_SPK * M_UTT)   // 32768
#define BM 128
#define GRID_G (NROWS / BM)     // 256

typedef __attribute__((ext_vector_type(8))) short short8v;  // 8 bf16
typedef __attribute__((ext_vector_type(4))) float f32x4;

__device__ __forceinline__ unsigned short f2bf(float f) {
    union { float f; unsigned int u; } v; v.f = f;
    unsigned int u = v.u;
    u += 0x7fffu + ((u >> 16) & 1u);   // RNE
    return (unsigned short)(u >> 16);
}

__device__ __forceinline__ void gload_lds16(const void* g, void* l) {
    __builtin_amdgcn_global_load_lds(
        (const __attribute__((address_space(1))) unsigned int*)g,
        (__attribute__((address_space(3))) unsigned int*)l, 16, 0, 0);
}

__device__ __forceinline__ float sigmoidf(float x) {
    return 1.f / (1.f + __expf(-x));
}

// ---- k1: emb fp32 -> ebf bf16 and ck bf16 (scaled by sgn(lw)/32) -----------
__global__ void __launch_bounds__(256) prep_kernel(const float* __restrict__ emb,
                                                   const float* __restrict__ lnw,
                                                   unsigned short* __restrict__ ebf,
                                                   unsigned short* __restrict__ ck) {
    __shared__ float part[2][D_DIM];
    const int n = blockIdx.x;
    const int t = threadIdx.x;
    const int d4 = (t & 127) * 4;
    const int mh = t >> 7;
    const float* base = emb + (size_t)n * M_UTT * D_DIM;
    unsigned short* obase = ebf + (size_t)n * M_UTT * D_DIM;

    float4 acc = {0.f, 0.f, 0.f, 0.f};
#pragma unroll
    for (int mm = 0; mm < 16; ++mm) {
        const int m = mh * 16 + mm;
        const float4 v = *reinterpret_cast<const float4*>(base + m * D_DIM + d4);
        acc.x += v.x; acc.y += v.y; acc.z += v.z; acc.w += v.w;
        ushort4 b;
        b.x = f2bf(v.x); b.y = f2bf(v.y); b.z = f2bf(v.z); b.w = f2bf(v.w);
        *reinterpret_cast<ushort4*>(obase + m * D_DIM + d4) = b;
    }
    *reinterpret_cast<float4*>(&part[mh][d4]) = acc;
    __syncthreads();
    if (t < 128) {
        const float sgn = (lnw[0] >= 0.f) ? 1.f : -1.f;
        const float sc = sgn * (1.f / 32.f);
        const int d = t * 4;
        const float4 a = *reinterpret_cast<const float4*>(&part[0][d]);
        const float4 b = *reinterpret_cast<const float4*>(&part[1][d]);
        ushort4 o;
        o.x = f2bf((a.x + b.x) * sc); o.y = f2bf((a.y + b.y) * sc);
        o.z = f2bf((a.z + b.z) * sc); o.w = f2bf((a.w + b.w) * sc);
        *reinterpret_cast<ushort4*>(ck + (size_t)n * D_DIM + d) = o;
    }
}

// ---- k2: A-resident pipelined GEMM + in-block row finish -------------------
__global__ void __launch_bounds__(512, 2)
gemm_kernel(const unsigned short* __restrict__ ebf,
            const unsigned short* __restrict__ ck,
            const float* __restrict__ lnw,
            const float* __restrict__ lnb,
            float* __restrict__ partsum) {
    __shared__ __align__(16) unsigned short As[BM * D_DIM];   // 128 KB
    __shared__ __align__(16) unsigned short Bring[2][8192];   // 2 x 16 KB

    const int tid  = threadIdx.x;
    const int lane = tid & 63;
    const int wv   = tid >> 6;
    const int lo   = lane & 15;
    const int hi   = lane >> 4;
    const int r0   = blockIdx.x * BM;

    // ---- prologue: issue A staging (16 x gload_lds16 per thread) ----
    // A layout: row*1024B + (chunk ^ (row&7))*16B  (chunk = k/8)
#pragma unroll
    for (int i = 0; i < 16; ++i) {
        const int s    = i * 512 + tid;
        const int row  = s >> 6;        // 64 16B-chunks per row
        const int chk  = s & 63;
        const unsigned short* src =
            ebf + (size_t)(r0 + row) * D_DIM + ((chk ^ (row & 7)) << 3);
        unsigned short* dst = As + ((size_t)i * 512 + wv * 64) * 8;
        gload_lds16(src, dst);
    }

    // ---- B staging: step u covers cols [(u>>4)*256,+256), k [(u&15)*32,+32)
    // slot layout: [kc(0..3)][col(0..255)] x 16B  (conflict-free reads)
    auto issueB = [&](int u) {
        unsigned short* ring = Bring[u & 1];
#pragma unroll
        for (int j = 0; j < 2; ++j) {
            const int s   = j * 512 + tid;
            const int kc  = s >> 8;
            const int col = s & 255;
            const unsigned short* src =
                ck + (size_t)((u >> 4) * 256 + col) * D_DIM + (u & 15) * 32 + kc * 8;
            unsigned short* dst = ring + ((size_t)j * 512 + wv * 64) * 8;
            gload_lds16(src, dst);
        }
    };
    issueB(0);
    issueB(1);

    const int wm = wv >> 2;   // 0..1 : 64-row half
    const int wn = wv & 3;    // 0..3 : 64-col quarter

    const float NEG = -1e30f;
    float mx[4][4], ow[4][4];
#pragma unroll
    for (int m = 0; m < 4; ++m)
#pragma unroll
        for (int r = 0; r < 4; ++r) { mx[m][r] = NEG; ow[m][r] = NEG; }

    const char* Ab = (const char*)As;

    for (int nt = 0; nt < 4; ++nt) {
        f32x4 acc[4][4];
#pragma unroll
        for (int m = 0; m < 4; ++m)
#pragma unroll
            for (int n = 0; n < 4; ++n) acc[m][n] = (f32x4){0.f, 0.f, 0.f, 0.f};

        for (int kt = 0; kt < 16; ++kt) {
            const int t = nt * 16 + kt;
            // gate: own loads for step t drained (A + B<=t); B_{t+1} pair stays
            if (t < 63) asm volatile("s_waitcnt vmcnt(2)" ::: "memory");
            else        asm volatile("s_waitcnt vmcnt(0)" ::: "memory");
            __builtin_amdgcn_s_barrier();   // cross-wave: slot t fully staged

            const char* Bb = (const char*)Bring[t & 1];
            short8v a[4], b[4];
#pragma unroll
            for (int m = 0; m < 4; ++m) {
                const int arow = wm * 64 + m * 16 + lo;
                const int slot = (kt * 4 + hi) ^ (arow & 7);
                a[m] = *reinterpret_cast<const short8v*>(Ab + arow * 1024 + slot * 16);
            }
#pragma unroll
            for (int n = 0; n < 4; ++n) {
                const int col = wn * 64 + n * 16 + lo;
                b[n] = *reinterpret_cast<const short8v*>(Bb + hi * 4096 + col * 16);
            }
#pragma unroll
            for (int m = 0; m < 4; ++m)
#pragma unroll
                for (int n = 0; n < 4; ++n)
                    acc[m][n] = __builtin_amdgcn_mfma_f32_16x16x32_bf16(a[m], b[n], acc[m][n], 0, 0, 0);

            // all my reads of slot t landed; rendezvous, then overwrite it
            asm volatile("s_waitcnt lgkmcnt(0)" ::: "memory");
            __builtin_amdgcn_s_barrier();
            if (t + 2 < 64) issueB(t + 2);
        }

        // fold this 256-col group into running row max / own capture
#pragma unroll
        for (int m = 0; m < 4; ++m)
#pragma unroll
            for (int n = 0; n < 4; ++n) {
                const int col = nt * 256 + wn * 64 + n * 16 + lo;
#pragma unroll
                for (int reg = 0; reg < 4; ++reg) {
                    const int rowg = r0 + wm * 64 + m * 16 + hi * 4 + reg;
                    const int spk  = rowg >> 5;
                    const float v  = acc[m][n][reg];
                    const bool dg  = (col == spk);
                    ow[m][reg] = dg ? v : ow[m][reg];
                    mx[m][reg] = fmaxf(mx[m][reg], dg ? NEG : v);
                }
            }
    }

    // ---- in-block finish ----
    __syncthreads();
    float* red = (float*)Bring;    // 8192 floats available
    const float lw = lnw[0];
    const float lb = lnb[0];

#pragma unroll
    for (int m = 0; m < 4; ++m)
#pragma unroll
        for (int reg = 0; reg < 4; ++reg) {
            float a = mx[m][reg], o = ow[m][reg];
#pragma unroll
            for (int mask = 1; mask < 16; mask <<= 1) {
                a = fmaxf(a, __shfl_xor(a, mask));
                o = fmaxf(o, __shfl_xor(o, mask));
            }
            if (lo == 0) {
                const int rl = wm * 64 + m * 16 + hi * 4 + reg;
                red[wn * 128 + rl]       = a;
                red[512 + wn * 128 + rl] = o;
            }
        }
    __syncthreads();

    if (tid < 128) {
        const float mo = fmaxf(fmaxf(red[tid], red[128 + tid]),
                               fmaxf(red[256 + tid], red[384 + tid]));
        const float op = fmaxf(fmaxf(red[512 + tid], red[640 + tid]),
                               fmaxf(red[768 + tid], red[896 + tid]));
        const float sgn = (lw >= 0.f) ? 1.f : -1.f;
        const float alw = fabsf(lw);
        const float s_own = sgn * op;
        const float ex    = (32.f * s_own - 1.f) * (1.f / 31.f);
        const float own_s = sigmoidf(lw * ex + lb);
        const float mo_s  = sigmoidf(alw * mo + lb);
        float loss = 1.f - own_s + mo_s;
        float corr = (sgn * ex >= mo) ? 1.f : 0.f;
#pragma unroll
        for (int mask = 1; mask < 64; mask <<= 1) {
            loss += __shfl_xor(loss, mask);
            corr += __shfl_xor(corr, mask);
        }
        if ((tid & 63) == 0) {
            red[1024 + (tid >> 6)] = loss;
            red[1026 + (tid >> 6)] = corr;
        }
    }
    __syncthreads();
    if (tid == 0) {
        partsum[blockIdx.x]          = red[1024] + red[1025];
        partsum[GRID_G + blockIdx.x] = red[1026] + red[1027];
    }
}

// ---- k3: final scalar reduce ----------------------------------------------
__global__ void __launch_bounds__(256) final_kernel(const float* __restrict__ partsum,
                                                    float* __restrict__ out) {
    __shared__ float sl[4], sc[4];
    const int t = threadIdx.x;
    float l = partsum[t];
    float c = partsum[GRID_G + t];
#pragma unroll
    for (int mask = 1; mask < 64; mask <<= 1) {
        l += __shfl_xor(l, mask);
        c += __shfl_xor(c, mask);
    }
    const int wv = t >> 6;
    if ((t & 63) == 0) { sl[wv] = l; sc[wv] = c; }
    __syncthreads();
    if (t == 0) {
        out[0] = (sl[0] + sl[1] + sl[2] + sl[3]) * (1.f / (float)NROWS);
        out[1] = (sc[0] + sc[1] + sc[2] + sc[3]) * (1.f / (float)NROWS);
    }
}

extern "C" void kernel_launch(void* const* d_in, const int* in_sizes, int n_in,
                              void* d_out, int out_size, void* d_ws, size_t ws_size,
                              hipStream_t stream) {
    (void)in_sizes; (void)n_in; (void)out_size; (void)ws_size;
    const float* emb = (const float*)d_in[0];
    const float* lnw = (const float*)d_in[3];
    const float* lnb = (const float*)d_in[4];
    float* out = (float*)d_out;

    char* ws = (char*)d_ws;
    unsigned short* ebf = (unsigned short*)ws;                                   // 32 MB
    unsigned short* ck  = (unsigned short*)(ws + (size_t)NROWS * D_DIM * 2);     // 1 MB
    float* partsum = (float*)(ws + (size_t)NROWS * D_DIM * 2 + (size_t)N_SPK * D_DIM * 2); // 2 KB

    prep_kernel<<<N_SPK, 256, 0, stream>>>(emb, lnw, ebf, ck);
    gemm_kernel<<<GRID_G, 512, 0, stream>>>(ebf, ck, lnw, lnb, partsum);
    final_kernel<<<1, 256, 0, stream>>>(partsum, out);
}

// Round 5
// 71.541 us; speedup vs baseline: 1.1018x; 1.1018x over previous
//
#include <hip/hip_runtime.h>

// GE2E loss, N=1024 spk, M=32 utt, D=512.
// v5: ring-4 deep-pipelined GEMM. Block = 256x256, BK=32, 16 K-tiles.
// LDS ring of 4 K-tile slots (A 16KB + B 16KB each = 128 KB): while computing
// tile t (slot t&3), stage tile t+2 (slot (t+2)&3, last read 2 barriers ago).
// ONE s_barrier + ONE counted s_waitcnt vmcnt(4) per K-tile (never 0 in
// steady state). 8 waves (2M x 4N), wave tile 128x64, 32 MFMA + 12
// ds_read_b128 per K-tile per wave. LDS layout = round-2's measured-0-conflict
// pattern: 128B lines (2 source rows/line), slot-XOR, global_load_lds with
// pre-swizzled source. Row max / own captured per block; cross-N-tile finish
// in rowred kernel.

#define N_SPK 1024
#define M_UTT 32
#define D_DIM 512
#define NROWS (N_SPK * M_UTT)   // 32768
#define BM 256
#define BN 256
#define NTILES (N_SPK / BN)     // 4
#define MTILES (NROWS / BM)     // 128
#define NWG (MTILES * NTILES)   // 512
#define NKT 16                  // 512 / 32

typedef __attribute__((ext_vector_type(8))) short short8v;  // 8 bf16
typedef __attribute__((ext_vector_type(4))) float f32x4;

__device__ __forceinline__ unsigned short f2bf(float f) {
    union { float f; unsigned int u; } v; v.f = f;
    unsigned int u = v.u;
    u += 0x7fffu + ((u >> 16) & 1u);   // RNE
    return (unsigned short)(u >> 16);
}

__device__ __forceinline__ void gload_lds16(const void* g, void* l) {
    __builtin_amdgcn_global_load_lds(
        (const __attribute__((address_space(1))) unsigned int*)g,
        (__attribute__((address_space(3))) unsigned int*)l, 16, 0, 0);
}

__device__ __forceinline__ float sigmoidf(float x) {
    return 1.f / (1.f + __expf(-x));
}

// ---- k1: emb fp32 -> ebf bf16 and ck bf16 (scaled by sgn(lw)/32) -----------
__global__ void __launch_bounds__(256) prep_kernel(const float* __restrict__ emb,
                                                   const float* __restrict__ lnw,
                                                   unsigned short* __restrict__ ebf,
                                                   unsigned short* __restrict__ ck) {
    __shared__ float part[2][D_DIM];
    const int n = blockIdx.x;
    const int t = threadIdx.x;
    const int d4 = (t & 127) * 4;
    const int mh = t >> 7;
    const float* base = emb + (size_t)n * M_UTT * D_DIM;
    unsigned short* obase = ebf + (size_t)n * M_UTT * D_DIM;

    float4 acc = {0.f, 0.f, 0.f, 0.f};
#pragma unroll
    for (int mm = 0; mm < 16; ++mm) {
        const int m = mh * 16 + mm;
        const float4 v = *reinterpret_cast<const float4*>(base + m * D_DIM + d4);
        acc.x += v.x; acc.y += v.y; acc.z += v.z; acc.w += v.w;
        ushort4 b;
        b.x = f2bf(v.x); b.y = f2bf(v.y); b.z = f2bf(v.z); b.w = f2bf(v.w);
        *reinterpret_cast<ushort4*>(obase + m * D_DIM + d4) = b;
    }
    *reinterpret_cast<float4*>(&part[mh][d4]) = acc;
    __syncthreads();
    if (t < 128) {
        const float sgn = (lnw[0] >= 0.f) ? 1.f : -1.f;
        const float sc = sgn * (1.f / 32.f);
        const int d = t * 4;
        const float4 a = *reinterpret_cast<const float4*>(&part[0][d]);
        const float4 b = *reinterpret_cast<const float4*>(&part[1][d]);
        ushort4 o;
        o.x = f2bf((a.x + b.x) * sc); o.y = f2bf((a.y + b.y) * sc);
        o.z = f2bf((a.z + b.z) * sc); o.w = f2bf((a.w + b.w) * sc);
        *reinterpret_cast<ushort4*>(ck + (size_t)n * D_DIM + d) = o;
    }
}

// ---- k2: ring-4 pipelined GEMM + per-block row max / own -------------------
__global__ void __launch_bounds__(512, 2)
gemm_kernel(const unsigned short* __restrict__ ebf,
            const unsigned short* __restrict__ ck,
            float* __restrict__ maxo_part,
            float* __restrict__ own_part) {
    // ring[slot][A=0/B=1][8192 ushorts]: 128 lines x 64 ushorts (128B) per half
    // line L holds source rows {2L, 2L+1}, k-window of 32: logical slot
    // l = (row&1)*4 + kchunk, physical = l ^ (L&7).
    __shared__ __align__(16) unsigned short ring[4][2][8192];   // 128 KB
    __shared__ float redmx[4][BM];                              // 4 KB
    __shared__ float redow[4][BM];                              // 4 KB

    const int tid  = threadIdx.x;
    const int lane = tid & 63;
    const int wv   = tid >> 6;
    const int lo   = lane & 15;
    const int hi   = lane >> 4;
    const int wm   = wv >> 2;   // 0..1 : 128-row half
    const int wn   = wv & 3;    // 0..3 : 64-col quarter

    // XCD-chunked bijective swizzle (512 wgs = 8 xcds x 64)
    const int raw = blockIdx.x;
    const int bid = (raw & 7) * 64 + (raw >> 3);
    const int mt  = bid >> 2;
    const int nt  = bid & 3;
    const int r0  = mt * BM;
    const int n0  = nt * BN;

    // ---- staging precompute: thread covers s in {tid, tid+512} ----
    const unsigned short* pA[2];
    const unsigned short* pB[2];
    int dstoff[2];
#pragma unroll
    for (int j = 0; j < 2; ++j) {
        const int s    = j * 512 + tid;
        const int L    = s >> 3;
        const int phys = s & 7;
        const int l    = phys ^ (L & 7);
        const int srow = 2 * L + (l >> 2);
        const int kch  = l & 3;
        pA[j] = ebf + (size_t)(r0 + srow) * D_DIM + kch * 8;
        pB[j] = ck  + (size_t)(n0 + srow) * D_DIM + kch * 8;
        dstoff[j] = s * 8;   // ushort units
    }

    auto stage = [&](int t) {
        const int slot = t & 3;
        const int ko = t * 32;
#pragma unroll
        for (int j = 0; j < 2; ++j) {
            gload_lds16(pA[j] + ko, &ring[slot][0][dstoff[j]]);
            gload_lds16(pB[j] + ko, &ring[slot][1][dstoff[j]]);
        }
    };

    // prologue: tiles 0,1 in flight; gate tile 0, keep tile 1 flying
    stage(0);
    stage(1);
    asm volatile("s_waitcnt vmcnt(4)" ::: "memory");
    __builtin_amdgcn_s_barrier();

    f32x4 acc[8][4];
#pragma unroll
    for (int m = 0; m < 8; ++m)
#pragma unroll
        for (int n = 0; n < 4; ++n) acc[m][n] = (f32x4){0.f, 0.f, 0.f, 0.f};

    // read addressing: phys slot is mf/nf-independent
    const int ph   = ((((lo & 1) << 2) + hi) ^ ((lo >> 1) & 7)) * 8; // ushorts
    const int lA0  = (wm * 64 + (lo >> 1)) * 64;                     // line base A
    const int lB0  = (wn * 32 + (lo >> 1)) * 64;                     // line base B

#pragma unroll 4
    for (int t = 0; t < NKT; ++t) {
        if (t < NKT - 2) stage(t + 2);

        const unsigned short* A = &ring[t & 3][0][0];
        const unsigned short* B = &ring[t & 3][1][0];

        short8v a[8], b[4];
#pragma unroll
        for (int mf = 0; mf < 8; ++mf)
            a[mf] = *reinterpret_cast<const short8v*>(A + lA0 + mf * 512 + ph);
#pragma unroll
        for (int nf = 0; nf < 4; ++nf)
            b[nf] = *reinterpret_cast<const short8v*>(B + lB0 + nf * 512 + ph);

        __builtin_amdgcn_s_setprio(1);
#pragma unroll
        for (int mf = 0; mf < 8; ++mf)
#pragma unroll
            for (int nf = 0; nf < 4; ++nf)
                acc[mf][nf] = __builtin_amdgcn_mfma_f32_16x16x32_bf16(
                    a[mf], b[nf], acc[mf][nf], 0, 0, 0);
        __builtin_amdgcn_s_setprio(0);

        // gate: tile t+1 (staged 1 group ago) must be landed for next group;
        // tile t+2 (4 loads just issued) stays in flight.
        if (t < NKT - 2)       asm volatile("s_waitcnt vmcnt(4)" ::: "memory");
        else if (t == NKT - 2) asm volatile("s_waitcnt vmcnt(0)" ::: "memory");
        if (t < NKT - 1) __builtin_amdgcn_s_barrier();
    }

    // ---- fold acc -> per-row max (diag excluded) + own capture ----
    const float NEG = -1e30f;
    float mx[8], ow[8];
    // per (mf): 4 regs each handled below; fold nf first per (mf, reg)
    __syncthreads();   // ring now dead; also joins all waves before reuse

#pragma unroll
    for (int mf = 0; mf < 8; ++mf) {
#pragma unroll
        for (int reg = 0; reg < 4; ++reg) {
            const int rowg = r0 + wm * 128 + mf * 16 + hi * 4 + reg;
            const int spk  = rowg >> 5;
            float m = NEG, o = NEG;
#pragma unroll
            for (int nf = 0; nf < 4; ++nf) {
                const int col = n0 + wn * 64 + nf * 16 + lo;
                const float v = acc[mf][nf][reg];
                const bool dg = (col == spk);
                o = dg ? v : o;
                m = fmaxf(m, dg ? NEG : v);
            }
            // reduce over the 16 lanes (lo) sharing this row
#pragma unroll
            for (int mask = 1; mask < 16; mask <<= 1) {
                m = fmaxf(m, __shfl_xor(m, mask));
                o = fmaxf(o, __shfl_xor(o, mask));
            }
            if (lo == 0) {
                const int rl = wm * 128 + mf * 16 + hi * 4 + reg;
                redmx[wn][rl] = m;
                redow[wn][rl] = o;
            }
            (void)mx; (void)ow;
        }
    }
    __syncthreads();

    if (tid < BM) {
        const float mo = fmaxf(fmaxf(redmx[0][tid], redmx[1][tid]),
                               fmaxf(redmx[2][tid], redmx[3][tid]));
        maxo_part[(size_t)nt * NROWS + r0 + tid] = mo;
        if (nt == (mt >> 5)) {
            const float op = fmaxf(fmaxf(redow[0][tid], redow[1][tid]),
                                   fmaxf(redow[2][tid], redow[3][tid]));
            own_part[r0 + tid] = op;
        }
    }
}

// ---- k3: per-row finish: combine 4 tile-maxes, sigmoid, loss/corr ---------
__global__ void __launch_bounds__(256) rowred_kernel(const float* __restrict__ maxo_part,
                                                     const float* __restrict__ own_part,
                                                     const float* __restrict__ lnw,
                                                     const float* __restrict__ lnb,
                                                     float* __restrict__ partsum) {
    const int r = blockIdx.x * 256 + threadIdx.x;
    const float lw = lnw[0], lb = lnb[0];
    const float sgn = (lw >= 0.f) ? 1.f : -1.f;
    const float alw = fabsf(lw);

    float mo = maxo_part[r];
#pragma unroll
    for (int nt2 = 1; nt2 < NTILES; ++nt2)
        mo = fmaxf(mo, maxo_part[(size_t)nt2 * NROWS + r]);
    const float ownp  = own_part[r];          // sgn-scaled raw dot e.ck_own
    const float s_own = sgn * ownp;
    const float ex    = (32.f * s_own - 1.f) * (1.f / 31.f);
    const float own_s = sigmoidf(lw * ex + lb);
    const float mo_s  = sigmoidf(alw * mo + lb);
    float loss = 1.f - own_s + mo_s;
    float corr = (sgn * ex >= mo) ? 1.f : 0.f;

#pragma unroll
    for (int mask = 1; mask < 64; mask <<= 1) {
        loss += __shfl_xor(loss, mask);
        corr += __shfl_xor(corr, mask);
    }
    __shared__ float sl[4], sc[4];
    const int wv = threadIdx.x >> 6;
    if ((threadIdx.x & 63) == 0) { sl[wv] = loss; sc[wv] = corr; }
    __syncthreads();
    if (threadIdx.x == 0) {
        partsum[blockIdx.x]       = sl[0] + sl[1] + sl[2] + sl[3];
        partsum[128 + blockIdx.x] = sc[0] + sc[1] + sc[2] + sc[3];
    }
}

// ---- k4: final scalar reduce ----------------------------------------------
__global__ void __launch_bounds__(128) final_kernel(const float* __restrict__ partsum,
                                                    float* __restrict__ out) {
    const int t = threadIdx.x;
    float l = partsum[t];
    float c = partsum[128 + t];
#pragma unroll
    for (int mask = 1; mask < 64; mask <<= 1) {
        l += __shfl_xor(l, mask);
        c += __shfl_xor(c, mask);
    }
    __shared__ float sl[2], sc[2];
    if ((t & 63) == 0) { sl[t >> 6] = l; sc[t >> 6] = c; }
    __syncthreads();
    if (t == 0) {
        out[0] = (sl[0] + sl[1]) * (1.f / (float)NROWS);
        out[1] = (sc[0] + sc[1]) * (1.f / (float)NROWS);
    }
}

extern "C" void kernel_launch(void* const* d_in, const int* in_sizes, int n_in,
                              void* d_out, int out_size, void* d_ws, size_t ws_size,
                              hipStream_t stream) {
    (void)in_sizes; (void)n_in; (void)out_size; (void)ws_size;
    const float* emb = (const float*)d_in[0];
    const float* lnw = (const float*)d_in[3];
    const float* lnb = (const float*)d_in[4];
    float* out = (float*)d_out;

    char* ws = (char*)d_ws;
    unsigned short* ebf = (unsigned short*)ws;                                   // 32 MB
    unsigned short* ck  = (unsigned short*)(ws + (size_t)NROWS * D_DIM * 2);     // 1 MB
    float* maxo_part = (float*)(ws + (size_t)NROWS * D_DIM * 2
                                   + (size_t)N_SPK * D_DIM * 2);                 // 512 KB
    float* own_part  = (float*)((char*)maxo_part + (size_t)NTILES * NROWS * 4);  // 128 KB
    float* partsum   = (float*)((char*)own_part + (size_t)NROWS * 4);            // 1 KB

    prep_kernel<<<N_SPK, 256, 0, stream>>>(emb, lnw, ebf, ck);
    gemm_kernel<<<NWG, 512, 0, stream>>>(ebf, ck, maxo_part, own_part);
    rowred_kernel<<<NROWS / 256, 256, 0, stream>>>(maxo_part, own_part, lnw, lnb, partsum);
    final_kernel<<<1, 128, 0, stream>>>(partsum, out);
}

// Round 6
// 66.361 us; speedup vs baseline: 1.1879x; 1.0781x over previous
//
#include <hip/hip_runtime.h>

// GE2E loss, N=1024 spk, M=32 utt, D=512.
// v6: 8-phase 256x256 GEMM (m201 template port). BK=64, 8 K-tiles, double-
// buffered LDS (2 x 64 KB). Per K-tile: 4 phases, each = {ds_read register
// subtile || stage issue -> barrier -> setprio(1) 16 MFMA setprio(0) ->
// barrier}. Counted vmcnt(4) once per K-tile (never 0 until the tail).
// 8 waves (2 wm x 4 wn), wave tile 128x64. LDS: 128B lines, chunk^(row&7)
// XOR swizzle (measured 0-conflict), staged via global_load_lds with
// pre-swizzled source. XCD-aware mapping: each XCD = 16 mt x 4 nt so the
// A-panels + full ck stay L2-resident per XCD.

#define N_SPK 1024
#define M_UTT 32
#define D_DIM 512
#define NROWS (N_SPK * M_UTT)   // 32768
#define BM 256
#define BN 256
#define NTILES (N_SPK / BN)     // 4
#define MTILES (NROWS / BM)     // 128
#define NWG (MTILES * NTILES)   // 512

typedef __attribute__((ext_vector_type(8))) short short8v;  // 8 bf16
typedef __attribute__((ext_vector_type(4))) float f32x4;

__device__ __forceinline__ unsigned short f2bf(float f) {
    union { float f; unsigned int u; } v; v.f = f;
    unsigned int u = v.u;
    u += 0x7fffu + ((u >> 16) & 1u);   // RNE
    return (unsigned short)(u >> 16);
}

__device__ __forceinline__ void gload_lds16(const void* g, void* l) {
    __builtin_amdgcn_global_load_lds(
        (const __attribute__((address_space(1))) unsigned int*)g,
        (__attribute__((address_space(3))) unsigned int*)l, 16, 0, 0);
}

__device__ __forceinline__ float sigmoidf(float x) {
    return 1.f / (1.f + __expf(-x));
}

template <int MH, int NH>
__device__ __forceinline__ void qmm(f32x4 (&acc)[8][4],
                                    const short8v (&a)[4][2],
                                    const short8v (&b)[2][2]) {
#pragma unroll
    for (int mf = 0; mf < 4; ++mf)
#pragma unroll
        for (int nf = 0; nf < 2; ++nf) {
            acc[MH * 4 + mf][NH * 2 + nf] = __builtin_amdgcn_mfma_f32_16x16x32_bf16(
                a[mf][0], b[nf][0], acc[MH * 4 + mf][NH * 2 + nf], 0, 0, 0);
            acc[MH * 4 + mf][NH * 2 + nf] = __builtin_amdgcn_mfma_f32_16x16x32_bf16(
                a[mf][1], b[nf][1], acc[MH * 4 + mf][NH * 2 + nf], 0, 0, 0);
        }
}

// ---- k1: emb fp32 -> ebf bf16 and ck bf16 (scaled by sgn(lw)/32) -----------
__global__ void __launch_bounds__(256) prep_kernel(const float* __restrict__ emb,
                                                   const float* __restrict__ lnw,
                                                   unsigned short* __restrict__ ebf,
                                                   unsigned short* __restrict__ ck) {
    __shared__ float part[2][D_DIM];
    const int n = blockIdx.x;
    const int t = threadIdx.x;
    const int d4 = (t & 127) * 4;
    const int mh = t >> 7;
    const float* base = emb + (size_t)n * M_UTT * D_DIM;
    unsigned short* obase = ebf + (size_t)n * M_UTT * D_DIM;

    float4 acc = {0.f, 0.f, 0.f, 0.f};
#pragma unroll
    for (int mm = 0; mm < 16; ++mm) {
        const int m = mh * 16 + mm;
        const float4 v = *reinterpret_cast<const float4*>(base + m * D_DIM + d4);
        acc.x += v.x; acc.y += v.y; acc.z += v.z; acc.w += v.w;
        ushort4 b;
        b.x = f2bf(v.x); b.y = f2bf(v.y); b.z = f2bf(v.z); b.w = f2bf(v.w);
        *reinterpret_cast<ushort4*>(obase + m * D_DIM + d4) = b;
    }
    *reinterpret_cast<float4*>(&part[mh][d4]) = acc;
    __syncthreads();
    if (t < 128) {
        const float sgn = (lnw[0] >= 0.f) ? 1.f : -1.f;
        const float sc = sgn * (1.f / 32.f);
        const int d = t * 4;
        const float4 a = *reinterpret_cast<const float4*>(&part[0][d]);
        const float4 b = *reinterpret_cast<const float4*>(&part[1][d]);
        ushort4 o;
        o.x = f2bf((a.x + b.x) * sc); o.y = f2bf((a.y + b.y) * sc);
        o.z = f2bf((a.z + b.z) * sc); o.w = f2bf((a.w + b.w) * sc);
        *reinterpret_cast<ushort4*>(ck + (size_t)n * D_DIM + d) = o;
    }
}

// ---- k2: 8-phase 256x256 GEMM + per-block row max / own --------------------
__global__ void __launch_bounds__(512, 2)
gemm_kernel(const unsigned short* __restrict__ ebf,
            const unsigned short* __restrict__ ck,
            float* __restrict__ maxo_part,
            float* __restrict__ own_part) {
    // Per buffer (64 KB): A = 256 rows x 64 k at bytes [0,32768): row*128 +
    // (chunk ^ (row&7))*16.  B same at bytes [32768,65536) indexed by col.
    __shared__ __align__(16) unsigned short ring[2][32768];   // 128 KB

    const int tid  = threadIdx.x;
    const int lane = tid & 63;
    const int wv   = tid >> 6;
    const int lo   = lane & 15;
    const int hi   = lane >> 4;
    const int wm   = wv >> 2;   // 0..1 : 128-row half
    const int wn   = wv & 3;    // 0..3 : 64-col quarter

    // XCD-aware mapping: xcd gets 16 consecutive mt x all 4 nt
    // (A-panels fetched once per XCD; ck fully L2-resident)
    const int raw   = blockIdx.x;
    const int xcd   = raw & 7;
    const int local = raw >> 3;          // 0..63
    const int mt    = xcd * 16 + (local >> 2);
    const int nt    = local & 3;
    const int r0    = mt * BM;
    const int n0    = nt * BN;

    // ---- staging map: half-tile = 128 rows x 64 k = 1024 16B-chunks ----
    // chunk s = j*512 + tid: row = s>>3, phys = s&7, logical l = phys^(row&7)
    const unsigned short* pA[2];
    const unsigned short* pB[2];
    int doff[2];
#pragma unroll
    for (int j = 0; j < 2; ++j) {
        const int s   = j * 512 + tid;
        const int row = s >> 3;
        const int l   = (s & 7) ^ (row & 7);
        pA[j] = ebf + (size_t)(r0 + row) * D_DIM + l * 8;
        pB[j] = ck  + (size_t)(n0 + row) * D_DIM + l * 8;
        doff[j] = s * 8;   // ushort units within a 16 KB half
    }

    auto stage_h = [&](int tile, int h) {
        unsigned short* dst = &ring[tile & 1][0];
        const int off = tile * 64 + h * (128 * D_DIM);
#pragma unroll
        for (int j = 0; j < 2; ++j) {
            gload_lds16(pA[j] + off, dst + h * 8192 + doff[j]);
            gload_lds16(pB[j] + off, dst + 16384 + h * 8192 + doff[j]);
        }
    };

    // prologue: tile0 fully + tile1 half0 in flight; gate tile0
    stage_h(0, 0);
    stage_h(0, 1);
    stage_h(1, 0);
    asm volatile("s_waitcnt vmcnt(4)" ::: "memory");
    __builtin_amdgcn_s_barrier();
    __builtin_amdgcn_sched_barrier(0);

    const int ph0   = (hi ^ (lo & 7)) * 16;        // kk=0 chunk byte offset
    const int ph1   = ((4 + hi) ^ (lo & 7)) * 16;  // kk=1
    const int arow0 = (wm * 128 + lo) * 128;       // A byte base (mf=0, mh=0)
    const int bcol0 = 32768 + (wn * 64 + lo) * 128;// B byte base (nf=0, nh=0)

    f32x4 acc[8][4];
#pragma unroll
    for (int am = 0; am < 8; ++am)
#pragma unroll
        for (int an = 0; an < 4; ++an) acc[am][an] = (f32x4){0.f, 0.f, 0.f, 0.f};

    short8v a[4][2], b0c[2][2], b1c[2][2];

    for (int t = 0; t < 8; ++t) {
        const char* bufp = (const char*)&ring[t & 1][0];

        // ---- phase 0: read a(mh0)+b(nh0); stage A1B1(t+1); Q(0,0) ----
#pragma unroll
        for (int mf = 0; mf < 4; ++mf) {
            a[mf][0] = *reinterpret_cast<const short8v*>(bufp + arow0 + mf * 2048 + ph0);
            a[mf][1] = *reinterpret_cast<const short8v*>(bufp + arow0 + mf * 2048 + ph1);
        }
#pragma unroll
        for (int nf = 0; nf < 2; ++nf) {
            b0c[nf][0] = *reinterpret_cast<const short8v*>(bufp + bcol0 + nf * 2048 + ph0);
            b0c[nf][1] = *reinterpret_cast<const short8v*>(bufp + bcol0 + nf * 2048 + ph1);
        }
        if (t < 7) stage_h(t + 1, 1);
        __builtin_amdgcn_s_barrier();
        __builtin_amdgcn_s_setprio(1);
        qmm<0, 0>(acc, a, b0c);
        __builtin_amdgcn_s_setprio(0);
        __builtin_amdgcn_s_barrier();

        // ---- phase 1: read b(nh1); Q(0,1) ----
#pragma unroll
        for (int nf = 0; nf < 2; ++nf) {
            b1c[nf][0] = *reinterpret_cast<const short8v*>(bufp + bcol0 + 4096 + nf * 2048 + ph0);
            b1c[nf][1] = *reinterpret_cast<const short8v*>(bufp + bcol0 + 4096 + nf * 2048 + ph1);
        }
        __builtin_amdgcn_s_barrier();
        __builtin_amdgcn_s_setprio(1);
        qmm<0, 1>(acc, a, b1c);
        __builtin_amdgcn_s_setprio(0);
        __builtin_amdgcn_s_barrier();

        // ---- phase 2: read a(mh1); Q(1,1) ----
#pragma unroll
        for (int mf = 0; mf < 4; ++mf) {
            a[mf][0] = *reinterpret_cast<const short8v*>(bufp + arow0 + 8192 + mf * 2048 + ph0);
            a[mf][1] = *reinterpret_cast<const short8v*>(bufp + arow0 + 8192 + mf * 2048 + ph1);
        }
        __builtin_amdgcn_s_barrier();
        __builtin_amdgcn_s_setprio(1);
        qmm<1, 1>(acc, a, b1c);
        __builtin_amdgcn_s_setprio(0);
        __builtin_amdgcn_s_barrier();

        // ---- phase 3: stage A0B0(t+2); Q(1,0); gate tile t+1 ----
        if (t < 6) stage_h(t + 2, 0);
        __builtin_amdgcn_s_barrier();
        __builtin_amdgcn_s_setprio(1);
        qmm<1, 0>(acc, a, b0c);
        __builtin_amdgcn_s_setprio(0);
        if (t < 6)       asm volatile("s_waitcnt vmcnt(4)" ::: "memory");
        else if (t == 6) asm volatile("s_waitcnt vmcnt(0)" ::: "memory");
        __builtin_amdgcn_s_barrier();
        __builtin_amdgcn_sched_barrier(0);
    }

    // ---- epilogue: fold acc -> per-row max (diag excluded) + own ----
    __syncthreads();
    float* red = (float*)&ring[0][0];   // ring dead; 2048 floats used
    const float NEG = -1e30f;

#pragma unroll
    for (int am = 0; am < 8; ++am) {
#pragma unroll
        for (int reg = 0; reg < 4; ++reg) {
            const int rl   = wm * 128 + am * 16 + hi * 4 + reg;
            const int rowg = r0 + rl;
            const int spk  = rowg >> 5;
            float m = NEG, o = NEG;
#pragma unroll
            for (int an = 0; an < 4; ++an) {
                const int col = n0 + wn * 64 + an * 16 + lo;
                const float v = acc[am][an][reg];
                const bool dg = (col == spk);
                o = dg ? v : o;
                m = fmaxf(m, dg ? NEG : v);
            }
#pragma unroll
            for (int mask = 1; mask < 16; mask <<= 1) {
                m = fmaxf(m, __shfl_xor(m, mask));
                o = fmaxf(o, __shfl_xor(o, mask));
            }
            if (lo == 0) {
                red[wn * 256 + rl]        = m;
                red[1024 + wn * 256 + rl] = o;
            }
        }
    }
    __syncthreads();

    if (tid < 256) {
        const float mo = fmaxf(fmaxf(red[tid], red[256 + tid]),
                               fmaxf(red[512 + tid], red[768 + tid]));
        maxo_part[(size_t)nt * NROWS + r0 + tid] = mo;
        if (nt == (mt >> 5)) {
            const float op = fmaxf(fmaxf(red[1024 + tid], red[1280 + tid]),
                                   fmaxf(red[1536 + tid], red[1792 + tid]));
            own_part[r0 + tid] = op;
        }
    }
}

// ---- k3: per-row finish: combine 4 tile-maxes, sigmoid, loss/corr ---------
__global__ void __launch_bounds__(256) rowred_kernel(const float* __restrict__ maxo_part,
                                                     const float* __restrict__ own_part,
                                                     const float* __restrict__ lnw,
                                                     const float* __restrict__ lnb,
                                                     float* __restrict__ partsum) {
    const int r = blockIdx.x * 256 + threadIdx.x;
    const float lw = lnw[0], lb = lnb[0];
    const float sgn = (lw >= 0.f) ? 1.f : -1.f;
    const float alw = fabsf(lw);

    float mo = maxo_part[r];
#pragma unroll
    for (int nt2 = 1; nt2 < NTILES; ++nt2)
        mo = fmaxf(mo, maxo_part[(size_t)nt2 * NROWS + r]);
    const float ownp  = own_part[r];          // sgn-scaled raw dot e.ck_own
    const float s_own = sgn * ownp;
    const float ex    = (32.f * s_own - 1.f) * (1.f / 31.f);
    const float own_s = sigmoidf(lw * ex + lb);
    const float mo_s  = sigmoidf(alw * mo + lb);
    float loss = 1.f - own_s + mo_s;
    float corr = (sgn * ex >= mo) ? 1.f : 0.f;

#pragma unroll
    for (int mask = 1; mask < 64; mask <<= 1) {
        loss += __shfl_xor(loss, mask);
        corr += __shfl_xor(corr, mask);
    }
    __shared__ float sl[4], sc[4];
    const int wv = threadIdx.x >> 6;
    if ((threadIdx.x & 63) == 0) { sl[wv] = loss; sc[wv] = corr; }
    __syncthreads();
    if (threadIdx.x == 0) {
        partsum[blockIdx.x]       = sl[0] + sl[1] + sl[2] + sl[3];
        partsum[128 + blockIdx.x] = sc[0] + sc[1] + sc[2] + sc[3];
    }
}

// ---- k4: final scalar reduce ----------------------------------------------
__global__ void __launch_bounds__(128) final_kernel(const float* __restrict__ partsum,
                                                    float* __restrict__ out) {
    const int t = threadIdx.x;
    float l = partsum[t];
    float c = partsum[128 + t];
#pragma unroll
    for (int mask = 1; mask < 64; mask <<= 1) {
        l += __shfl_xor(l, mask);
        c += __shfl_xor(c, mask);
    }
    __shared__ float sl[2], sc[2];
    if ((t & 63) == 0) { sl[t >> 6] = l; sc[t >> 6] = c; }
    __syncthreads();
    if (t == 0) {
        out[0] = (sl[0] + sl[1]) * (1.f / (float)NROWS);
        out[1] = (sc[0] + sc[1]) * (1.f / (float)NROWS);
    }
}

extern "C" void kernel_launch(void* const* d_in, const int* in_sizes, int n_in,
                              void* d_out, int out_size, void* d_ws, size_t ws_size,
                              hipStream_t stream) {
    (void)in_sizes; (void)n_in; (void)out_size; (void)ws_size;
    const float* emb = (const float*)d_in[0];
    const float* lnw = (const float*)d_in[3];
    const float* lnb = (const float*)d_in[4];
    float* out = (float*)d_out;

    char* ws = (char*)d_ws;
    unsigned short* ebf = (unsigned short*)ws;                                   // 32 MB
    unsigned short* ck  = (unsigned short*)(ws + (size_t)NROWS * D_DIM * 2);     // 1 MB
    float* maxo_part = (float*)(ws + (size_t)NROWS * D_DIM * 2
                                   + (size_t)N_SPK * D_DIM * 2);                 // 512 KB
    float* own_part  = (float*)((char*)maxo_part + (size_t)NTILES * NROWS * 4);  // 128 KB
    float* partsum   = (float*)((char*)own_part + (size_t)NROWS * 4);            // 1 KB

    prep_kernel<<<N_SPK, 256, 0, stream>>>(emb, lnw, ebf, ck);
    gemm_kernel<<<NWG, 512, 0, stream>>>(ebf, ck, maxo_part, own_part);
    rowred_kernel<<<NROWS / 256, 256, 0, stream>>>(maxo_part, own_part, lnw, lnb, partsum);
    final_kernel<<<1, 128, 0, stream>>>(partsum, out);
}